// Round 7
// baseline (9582.393 us; speedup 1.0000x reference)
//
#include <hip/hip_runtime.h>
#include <stdint.h>

#define B_   128
#define T_   64
#define V_   1024
#define TS_  64
#define H_   512
#define K_   (V_ + TS_)   // 1088

// ---------------------------------------------------------------------------
// Fused time-aware GRU scan, round 7.
//
// 64 WGs x 320 threads (5 waves): wave 0 = dedicated poller (owns no h),
// waves 1..4 = workers; global worker wq = blk*4+(wave-1) owns h[2wq],
// h[2wq+1] with round-2/6 math (register weights, 8-value butterfly).
//
// History: r2 11.2ms (256 pollers, contention); r3 18.3ms (fences in spin =
// L1/L2 melt); r6 8.97ms PASS (64 leader-pollers + LDS broadcast). r6 poll
// reduction 4x only bought 1.27x => ~2.0us/step FIXED term = store->observe
// visibility, inflated by (a) unthrottled sweep traffic queueing ahead of
// the stores, (b) leader double-duty (its own compute inside the chain).
//
// r7 changes (congestion theory):
//   1. leader owns NO h and does NO x-dots; after releasing hs(v) at the
//      barrier it immediately polls v+1, overlapping workers' compute.
//      LDS hs double-buffered [2][512].
//   2. s_sleep(2) backoff between FAILED sweeps (first sweep immediate).
//   3. workers s_waitcnt vmcnt(0) after the tagged store BEFORE issuing
//      prefetch loads (own loads can't queue ahead of own store).
//
// Safety induction (unchanged): tag v+1 is stored only after the worker's
// sync(v), which requires its leader observed ALL tags v; any tag v was
// stored after that WG's sync(v-1), i.e. after its leader finished reading
// slot (v-1)&1 == (v+1)&1. So all leaders are done with a slot before any
// worker overwrites it. hs[s] rewrites are separated by >=1 barrier from
// all reads of the previous occupant. Bounded spin watchdog (2^21 iters)
// turns any protocol bug into a fast absmax-fail instead of a dead box.
//
// Masked steps (t >= lens[b]) skipped; chain = sum(lens) ~ 4032 steps.
// Workspace: 8KB tagged h_buf. Poison tag 0xAAAAAAAA != any ver (< 8200).
// ---------------------------------------------------------------------------

__device__ __forceinline__ float sigmoidf_(float x) {
    return 1.0f / (1.0f + __expf(-x));
}
__device__ __forceinline__ float tanhf_(float x) {
    x = fminf(fmaxf(x, -15.0f), 15.0f);
    const float e = __expf(2.0f * x);
    return (e - 1.0f) / (e + 1.0f);
}

__global__ __launch_bounds__(320, 1) void gru_fused(
    const float* __restrict__ visit_emb, const float* __restrict__ intervals,
    const float* __restrict__ W_time, const float* __restrict__ b_time,
    const float* __restrict__ W_ih, const float* __restrict__ W_hh,
    const float* __restrict__ b_ih, const float* __restrict__ b_hh,
    const int* __restrict__ lens, uint64_t* h_buf /* [2][H_] tagged */,
    float* __restrict__ out)
{
    const int  lane      = threadIdx.x & 63;
    const int  wave      = threadIdx.x >> 6;            // 0..4
    const bool is_leader = (wave == 0);
    const int  wq        = blockIdx.x * 4 + (wave - 1); // workers: 0..255
    const int  j0        = wq * 2;
    const int  j1        = j0 + 1;

    __shared__ float hs[2][H_];                         // double-buffered h

    // ---- worker-only: register-resident weights -------------------------
    float wr0[8], wr1[8], wz0[8], wz1[8], wn0[8], wn1[8];
    float ir0[17], ir1[17], iz0[17], iz1[17], in0[17], in1[17];
    float wt = 0, bt = 0;
    float bir0 = 0, bir1 = 0, biz0 = 0, biz1 = 0, bin0 = 0, bin1 = 0;
    float bhr0 = 0, bhr1 = 0, bhz0 = 0, bhz1 = 0, bhn0 = 0, bhn1 = 0;

    if (!is_leader) {
        #pragma unroll
        for (int u = 0; u < 8; ++u) {
            const int k = lane + 64 * u;
            wr0[u] = W_hh[(size_t)j0 * H_ + k];
            wr1[u] = W_hh[(size_t)j1 * H_ + k];
            wz0[u] = W_hh[(size_t)(H_ + j0) * H_ + k];
            wz1[u] = W_hh[(size_t)(H_ + j1) * H_ + k];
            wn0[u] = W_hh[(size_t)(2 * H_ + j0) * H_ + k];
            wn1[u] = W_hh[(size_t)(2 * H_ + j1) * H_ + k];
        }
        #pragma unroll
        for (int u = 0; u < 16; ++u) {
            const int k = lane + 64 * u;
            ir0[u] = W_ih[(size_t)j0 * K_ + k];
            ir1[u] = W_ih[(size_t)j1 * K_ + k];
            iz0[u] = W_ih[(size_t)(H_ + j0) * K_ + k];
            iz1[u] = W_ih[(size_t)(H_ + j1) * K_ + k];
            in0[u] = W_ih[(size_t)(2 * H_ + j0) * K_ + k];
            in1[u] = W_ih[(size_t)(2 * H_ + j1) * K_ + k];
        }
        ir0[16] = W_ih[(size_t)j0 * K_ + V_ + lane];
        ir1[16] = W_ih[(size_t)j1 * K_ + V_ + lane];
        iz0[16] = W_ih[(size_t)(H_ + j0) * K_ + V_ + lane];
        iz1[16] = W_ih[(size_t)(H_ + j1) * K_ + V_ + lane];
        in0[16] = W_ih[(size_t)(2 * H_ + j0) * K_ + V_ + lane];
        in1[16] = W_ih[(size_t)(2 * H_ + j1) * K_ + V_ + lane];

        wt = W_time[lane];  bt = b_time[lane];
        bir0 = b_ih[j0];          bir1 = b_ih[j1];
        biz0 = b_ih[H_ + j0];     biz1 = b_ih[H_ + j1];
        bin0 = b_ih[2 * H_ + j0]; bin1 = b_ih[2 * H_ + j1];
        bhr0 = b_hh[j0];          bhr1 = b_hh[j1];
        bhz0 = b_hh[H_ + j0];     bhz1 = b_hh[H_ + j1];
        bhn0 = b_hh[2 * H_ + j0]; bhn1 = b_hh[2 * H_ + j1];
    }

    float hj0 = 0.0f, hj1 = 0.0f;
    uint32_t ver  = 1;   // ver 1 == initial zero state, lives in slot 1
    uint32_t dead = 0;   // leader watchdog

    // workers publish initial tagged zero state (tag carries the flag)
    if (!is_leader && lane < 2)
        __hip_atomic_store(&h_buf[(ver & 1) * H_ + j0 + lane],
                           (uint64_t)ver << 32,
                           __ATOMIC_RELAXED, __HIP_MEMORY_SCOPE_AGENT);

    float xv[16];     // worker: current step's visit row (prefetched)
    float iv = 0.0f;

    for (int b = 0; b < B_; ++b) {
        const int L = lens[b];
        if (!is_leader && L > 0) {
            iv = intervals[b * T_];
            const float* vrow = visit_emb + (size_t)(b * T_) * V_;
            #pragma unroll
            for (int u = 0; u < 16; ++u) xv[u] = vrow[lane + 64 * u];
        }
        for (int t = 0; t < L; ++t) {
            float ar0, ar1, az0, az1, xn0, xn1;
            if (!is_leader) {
                // ---- x-side dots (h-independent, pre-barrier) -----------
                const float xt = fmaf(iv, wt, bt);
                ar0 = ir0[16] * xt; ar1 = ir1[16] * xt;
                az0 = iz0[16] * xt; az1 = iz1[16] * xt;
                xn0 = in0[16] * xt; xn1 = in1[16] * xt;
                #pragma unroll
                for (int u = 0; u < 16; ++u) {
                    ar0 = fmaf(ir0[u], xv[u], ar0);
                    ar1 = fmaf(ir1[u], xv[u], ar1);
                    az0 = fmaf(iz0[u], xv[u], az0);
                    az1 = fmaf(iz1[u], xv[u], az1);
                    xn0 = fmaf(in0[u], xv[u], xn0);
                    xn1 = fmaf(in1[u], xv[u], xn1);
                }
            } else {
                // ---- leader: poll tagged words, stage into LDS ----------
                const uint64_t* src = h_buf + (ver & 1) * H_;
                uint64_t w[8];
                if (!dead) {
                    uint32_t tries = 0;
                    bool first = true, ok;
                    do {
                        if (!first) __builtin_amdgcn_s_sleep(2);  // backoff
                        first = false;
                        ok = true;
                        #pragma unroll
                        for (int u = 0; u < 8; ++u) {
                            w[u] = __hip_atomic_load(&src[lane + 64 * u],
                                                     __ATOMIC_RELAXED,
                                                     __HIP_MEMORY_SCOPE_AGENT);
                            ok = ok && ((uint32_t)(w[u] >> 32) == ver);
                        }
                        if (++tries > (1u << 21)) { dead = 1; break; }
                    } while (!__all(ok));
                } else {
                    #pragma unroll
                    for (int u = 0; u < 8; ++u)
                        w[u] = __hip_atomic_load(&src[lane + 64 * u],
                                                 __ATOMIC_RELAXED,
                                                 __HIP_MEMORY_SCOPE_AGENT);
                }
                float* dsth = hs[ver & 1];
                #pragma unroll
                for (int u = 0; u < 8; ++u)
                    dsth[lane + 64 * u] = __uint_as_float((uint32_t)w[u]);
            }
            __syncthreads();   // releases hs(ver); leader then polls ver+1

            if (!is_leader) {
                const float* srch = hs[ver & 1];
                float h[8];
                #pragma unroll
                for (int u = 0; u < 8; ++u) h[u] = srch[lane + 64 * u];

                float hn0 = 0.0f, hn1 = 0.0f;
                #pragma unroll
                for (int u = 0; u < 8; ++u) {
                    ar0 = fmaf(wr0[u], h[u], ar0);
                    ar1 = fmaf(wr1[u], h[u], ar1);
                    az0 = fmaf(wz0[u], h[u], az0);
                    az1 = fmaf(wz1[u], h[u], az1);
                    hn0 = fmaf(wn0[u], h[u], hn0);
                    hn1 = fmaf(wn1[u], h[u], hn1);
                }
                #pragma unroll
                for (int m = 1; m < 64; m <<= 1) {
                    ar0 += __shfl_xor(ar0, m, 64);
                    ar1 += __shfl_xor(ar1, m, 64);
                    az0 += __shfl_xor(az0, m, 64);
                    az1 += __shfl_xor(az1, m, 64);
                    xn0 += __shfl_xor(xn0, m, 64);
                    xn1 += __shfl_xor(xn1, m, 64);
                    hn0 += __shfl_xor(hn0, m, 64);
                    hn1 += __shfl_xor(hn1, m, 64);
                }

                const float r0 = sigmoidf_(ar0 + bir0 + bhr0);
                const float r1 = sigmoidf_(ar1 + bir1 + bhr1);
                const float z0 = sigmoidf_(az0 + biz0 + bhz0);
                const float z1 = sigmoidf_(az1 + biz1 + bhz1);
                const float n0 = tanhf_(xn0 + bin0 + r0 * (hn0 + bhn0));
                const float n1 = tanhf_(xn1 + bin1 + r1 * (hn1 + bhn1));
                hj0 = (1.0f - z0) * n0 + z0 * hj0;
                hj1 = (1.0f - z1) * n1 + z1 * hj1;

                // ---- publish tagged h(ver+1), drain store ---------------
                uint64_t* dst = h_buf + ((ver + 1) & 1) * H_;
                const float hv = (lane == 0) ? hj0 : hj1;
                if (lane < 2)
                    __hip_atomic_store(&dst[j0 + lane],
                        ((uint64_t)(ver + 1) << 32) |
                        (uint64_t)__float_as_uint(hv),
                        __ATOMIC_RELAXED, __HIP_MEMORY_SCOPE_AGENT);
                __asm__ volatile("s_waitcnt vmcnt(0)" ::: "memory");

                // ---- prefetch next x row (after the store drained) ------
                if (t + 1 < L) {
                    iv = intervals[b * T_ + t + 1];
                    const float* vrow =
                        visit_emb + (size_t)(b * T_ + t + 1) * V_;
                    #pragma unroll
                    for (int u = 0; u < 16; ++u)
                        xv[u] = vrow[lane + 64 * u];
                }
            }
            ++ver;
        }
        // out[b] = h after sample b's (possibly empty) segment
        if (!is_leader && lane < 2)
            out[b * H_ + j0 + lane] = (lane == 0) ? hj0 : hj1;
    }
}

// ---------------------------------------------------------------------------
extern "C" void kernel_launch(void* const* d_in, const int* in_sizes, int n_in,
                              void* d_out, int out_size, void* d_ws, size_t ws_size,
                              hipStream_t stream)
{
    const float* visit_emb = (const float*)d_in[0];
    const float* intervals = (const float*)d_in[1];
    const float* W_time    = (const float*)d_in[2];
    const float* b_time    = (const float*)d_in[3];
    const float* W_ih      = (const float*)d_in[4];
    const float* W_hh      = (const float*)d_in[5];
    const float* b_ih      = (const float*)d_in[6];
    const float* b_hh      = (const float*)d_in[7];
    const int*   lens      = (const int*)d_in[8];
    float*       out       = (float*)d_out;

    // workspace: tagged h exchange buffer (2 x 512 x u64 = 8 KiB)
    uint64_t* h_buf = (uint64_t*)d_ws;

    gru_fused<<<64, 320, 0, stream>>>(visit_emb, intervals, W_time, b_time,
                                      W_ih, W_hh, b_ih, b_hh, lens, h_buf, out);
}